// Round 5
// baseline (819.722 us; speedup 1.0000x reference)
//
#include <hip/hip_runtime.h>
#include <stdint.h>

typedef __attribute__((ext_vector_type(8))) short short8;
typedef __attribute__((ext_vector_type(4))) float floatx4;

#define T_TOK 4096
#define D_DIM 1024
#define H_DIM 4096
#define E_NUM 8
#define MAX_TILES 71            // sum_e ceil(cnt_e/128) <= 64 + 7
#define PLANE (8192ULL * 1024ULL)   // floats per split-K partial plane

static __device__ __forceinline__ ushort f2bf(float f) {
    uint32_t u = __float_as_uint(f);
    u += 0x7FFF + ((u >> 16) & 1);   // round-to-nearest-even
    return (ushort)(u >> 16);
}

static __device__ __forceinline__ uint4 pack8(float4 a, float4 b) {
    union { ushort u[8]; uint4 v; } r;
    r.u[0] = f2bf(a.x); r.u[1] = f2bf(a.y); r.u[2] = f2bf(a.z); r.u[3] = f2bf(a.w);
    r.u[4] = f2bf(b.x); r.u[5] = f2bf(b.y); r.u[6] = f2bf(b.z); r.u[7] = f2bf(b.w);
    return r.v;
}

// async global->LDS, 16B per lane; LDS dest = wave-uniform base + lane*16
static __device__ __forceinline__ void gl_lds16(const void* g, void* l) {
    __builtin_amdgcn_global_load_lds(
        (const __attribute__((address_space(1))) uint32_t*)g,
        (__attribute__((address_space(3))) uint32_t*)l, 16, 0, 0);
}

// ---------------- fused f32 -> bf16 bulk convert (x, w1, w2 in one grid) -----
__global__ __launch_bounds__(256) void cvt_all_kernel(
    const float* __restrict__ x,  ushort* __restrict__ xbf,
    const float* __restrict__ w1, ushort* __restrict__ w1bf,
    const float* __restrict__ w2, ushort* __restrict__ w2bf)
{
    const size_t NX = (size_t)T_TOK * D_DIM;            // 4M
    const size_t NW = (size_t)E_NUM * H_DIM * D_DIM;    // 32M
    size_t i = ((size_t)blockIdx.x * 256 + threadIdx.x) * 8;
    const float* src; ushort* dst; size_t j;
    if (i < NX)           { src = x;  dst = xbf;  j = i; }
    else if (i < NX + NW) { src = w1; dst = w1bf; j = i - NX; }
    else                  { src = w2; dst = w2bf; j = i - NX - NW; }
    float4 a = *(const float4*)(src + j);
    float4 b = *(const float4*)(src + j + 4);
    *(uint4*)(dst + j) = pack8(a, b);
}

// ---------------- Router: logits -> softmax -> top2 -> renorm (all f32) ------
__global__ __launch_bounds__(256) void router_kernel(
    const float* __restrict__ x, const float* __restrict__ rw,
    int* __restrict__ counts, int* __restrict__ topi, float* __restrict__ topw)
{
    __shared__ float rwS[E_NUM * D_DIM];             // 32 KB
    int tid = threadIdx.x;
    for (int i = tid; i < E_NUM * D_DIM / 4; i += 256)
        ((float4*)rwS)[i] = ((const float4*)rw)[i];
    __syncthreads();

    int wave = tid >> 6, lane = tid & 63;
    int t = blockIdx.x * 4 + wave;
    const float* xr = x + (size_t)t * D_DIM;

    float acc[E_NUM];
#pragma unroll
    for (int e = 0; e < E_NUM; e++) acc[e] = 0.f;

    float xv[16];
#pragma unroll
    for (int j = 0; j < 4; j++)
        *(float4*)&xv[j * 4] = ((const float4*)xr)[lane * 4 + j];
#pragma unroll
    for (int j = 0; j < 16; j++) {
        int idx = lane * 16 + j;
#pragma unroll
        for (int e = 0; e < E_NUM; e++)
            acc[e] += xv[j] * rwS[e * D_DIM + idx];
    }
#pragma unroll
    for (int e = 0; e < E_NUM; e++)
        for (int off = 32; off > 0; off >>= 1)
            acc[e] += __shfl_xor(acc[e], off, 64);

    if (lane == 0) {
        float mx = acc[0];
        for (int e = 1; e < E_NUM; e++) mx = fmaxf(mx, acc[e]);
        float p[E_NUM];
        for (int e = 0; e < E_NUM; e++) p[e] = expf(acc[e] - mx);
        int i0 = 0;
        for (int e = 1; e < E_NUM; e++) if (p[e] > p[i0]) i0 = e;   // lowest-idx tie-break
        int i1 = (i0 == 0) ? 1 : 0;
        for (int e = 0; e < E_NUM; e++) if (e != i0 && p[e] > p[i1]) i1 = e;
        float w0 = p[i0], w1 = p[i1], sw = w0 + w1;
        w0 /= sw; w1 /= sw;
        topi[t * 2] = i0; topi[t * 2 + 1] = i1;
        topw[t * 2] = w0; topw[t * 2 + 1] = w1;
        atomicAdd(&counts[i0], 1);
        atomicAdd(&counts[i1], 1);
    }
}

// offsets + exact tile list (kills dead blocks in the GEMM grids)
__global__ void offsets_tiles_kernel(const int* __restrict__ counts,
                                     int* __restrict__ offsets, int* __restrict__ cursors,
                                     int* __restrict__ tile_e, int* __restrict__ tile_m0)
{
    if (threadIdx.x == 0 && blockIdx.x == 0) {
        int off = 0, n = 0;
        for (int e = 0; e < E_NUM; e++) {
            offsets[e] = off; cursors[e] = off; off += counts[e];
            for (int m0 = 0; m0 < counts[e]; m0 += 128) {
                tile_e[n] = e; tile_m0[n] = m0; n++;
            }
        }
        for (; n < MAX_TILES; n++) tile_e[n] = -1;
    }
}

__global__ __launch_bounds__(256) void assign_kernel(
    const int* __restrict__ topi, const float* __restrict__ topw,
    int* __restrict__ cursors, int* __restrict__ pair_token, float* __restrict__ pair_w,
    int* __restrict__ ppos)
{
    int t = blockIdx.x * 256 + threadIdx.x;
    if (t >= T_TOK) return;
    for (int k = 0; k < 2; k++) {
        int e = topi[t * 2 + k];
        int pos = atomicAdd(&cursors[e], 1);
        pair_token[pos] = t;
        pair_w[pos] = topw[t * 2 + k];
        ppos[t * 2 + k] = pos;
    }
}

// ---------------- FFN layer 1: h = gelu(xbf @ w1bf^T + b1) -------------------
// 128x128 tile, BK=64, XOR-swizzled 16B-chunk LDS layout, global_load_lds(16B).
__global__ __launch_bounds__(256) void ffn1_kernel(
    const ushort* __restrict__ xbf, const ushort* __restrict__ w1bf,
    const float* __restrict__ bias1,
    const int* __restrict__ counts, const int* __restrict__ offsets,
    const int* __restrict__ tile_e, const int* __restrict__ tile_m0,
    const int* __restrict__ pair_token, ushort* __restrict__ h)
{
    int e = tile_e[blockIdx.x];
    if (e < 0) return;
    int m0 = tile_m0[blockIdx.x];
    int cnt = counts[e];
    int off = offsets[e];
    int n0 = blockIdx.y * 128;

    __shared__ ushort As[128 * 64];   // 16 KB
    __shared__ ushort Bs[128 * 64];   // 16 KB

    const int t = threadIdx.x;
    const int wave = t >> 6, lane = t & 63;
    const int wm = (wave >> 1) * 64, wn = (wave & 1) * 64;
    const int quad = lane >> 4, l16 = lane & 15;

    // staging: call j covers rows [j*32 + wave*8, +8); lane>>3 = row-in-8, lane&7 = chunk pos
    const int rsub = lane >> 3;
    const int cpos = lane & 7;
    const int srcElem = (cpos ^ rsub) * 8;   // XOR swizzle (row&7 == rsub for these rows)

    const ushort* aP[4];
    const ushort* bP[4];
#pragma unroll
    for (int j = 0; j < 4; j++) {
        int row = j * 32 + wave * 8 + rsub;
        int gr = m0 + row; if (gr >= cnt) gr = cnt - 1;
        aP[j] = xbf + (size_t)pair_token[off + gr] * D_DIM + srcElem;
        bP[j] = w1bf + ((size_t)e * H_DIM + n0 + row) * D_DIM + srcElem;
    }
    char* AsB = (char*)As;
    char* BsB = (char*)Bs;
    int seg[4];
#pragma unroll
    for (int j = 0; j < 4; j++) seg[j] = j * 4096 + wave * 1024;

    int rowA[4], rowB[4];
#pragma unroll
    for (int i = 0; i < 4; i++) {
        rowA[i] = (wm + i * 16 + l16) * 128;
        rowB[i] = (wn + i * 16 + l16) * 128;
    }
    const int x7 = l16 & 7;

    floatx4 acc[4][4] = {};

    for (int k0 = 0; k0 < D_DIM; k0 += 64) {
        __syncthreads();
#pragma unroll
        for (int j = 0; j < 4; j++) gl_lds16(aP[j], AsB + seg[j]);
#pragma unroll
        for (int j = 0; j < 4; j++) gl_lds16(bP[j], BsB + seg[j]);
#pragma unroll
        for (int j = 0; j < 4; j++) { aP[j] += 64; bP[j] += 64; }
        __syncthreads();

#pragma unroll
        for (int kk = 0; kk < 2; kk++) {
            const int co = ((((kk << 2) | quad)) ^ x7) << 4;
            short8 av[4], bv[4];
#pragma unroll
            for (int i = 0; i < 4; i++) av[i] = *(const short8*)(AsB + rowA[i] + co);
#pragma unroll
            for (int i = 0; i < 4; i++) bv[i] = *(const short8*)(BsB + rowB[i] + co);
#pragma unroll
            for (int mi = 0; mi < 4; mi++)
#pragma unroll
                for (int ni = 0; ni < 4; ni++)
                    acc[mi][ni] = __builtin_amdgcn_mfma_f32_16x16x32_bf16(av[mi], bv[ni], acc[mi][ni], 0, 0, 0);
        }
    }

    float bb[4];
#pragma unroll
    for (int ni = 0; ni < 4; ni++) bb[ni] = bias1[e * H_DIM + n0 + wn + ni * 16 + l16];

#pragma unroll
    for (int mi = 0; mi < 4; mi++) {
#pragma unroll
        for (int reg = 0; reg < 4; reg++) {
            int gm = m0 + wm + mi * 16 + quad * 4 + reg;
            if (gm < cnt) {
                ushort* hrow = h + (size_t)(off + gm) * H_DIM + n0 + wn;
#pragma unroll
                for (int ni = 0; ni < 4; ni++) {
                    float v = acc[mi][ni][reg] + bb[ni];
                    v = 0.5f * v * (1.f + erff(v * 0.70710678118654752f));
                    hrow[ni * 16 + l16] = f2bf(v);
                }
            }
        }
    }
}

// ------- FFN layer 2 (split-K x2): o_part[kc] = cw * (h[:,kc] @ w2[:,kc]^T [+ b2]) -------
__global__ __launch_bounds__(256) void ffn2_kernel(
    const ushort* __restrict__ h, const ushort* __restrict__ w2bf,
    const float* __restrict__ bias2,
    const int* __restrict__ counts, const int* __restrict__ offsets,
    const int* __restrict__ tile_e, const int* __restrict__ tile_m0,
    const float* __restrict__ pair_w, float* __restrict__ o_part)
{
    int e = tile_e[blockIdx.x];
    if (e < 0) return;
    int m0 = tile_m0[blockIdx.x];
    int cnt = counts[e];
    int off = offsets[e];
    int n0 = blockIdx.y * 128;
    int kc = blockIdx.z;                      // 0 or 1
    const size_t kbase = (size_t)kc * (H_DIM / 2);

    __shared__ ushort As[128 * 64];
    __shared__ ushort Bs[128 * 64];

    const int t = threadIdx.x;
    const int wave = t >> 6, lane = t & 63;
    const int wm = (wave >> 1) * 64, wn = (wave & 1) * 64;
    const int quad = lane >> 4, l16 = lane & 15;

    const int rsub = lane >> 3;
    const int cpos = lane & 7;
    const int srcElem = (cpos ^ rsub) * 8;

    const ushort* aP[4];
    const ushort* bP[4];
#pragma unroll
    for (int j = 0; j < 4; j++) {
        int row = j * 32 + wave * 8 + rsub;
        int gr = m0 + row; if (gr >= cnt) gr = cnt - 1;
        aP[j] = h + (size_t)(off + gr) * H_DIM + kbase + srcElem;
        bP[j] = w2bf + ((size_t)e * D_DIM + n0 + row) * H_DIM + kbase + srcElem;
    }
    char* AsB = (char*)As;
    char* BsB = (char*)Bs;
    int seg[4];
#pragma unroll
    for (int j = 0; j < 4; j++) seg[j] = j * 4096 + wave * 1024;

    int rowA[4], rowB[4];
#pragma unroll
    for (int i = 0; i < 4; i++) {
        rowA[i] = (wm + i * 16 + l16) * 128;
        rowB[i] = (wn + i * 16 + l16) * 128;
    }
    const int x7 = l16 & 7;

    floatx4 acc[4][4] = {};

    for (int k0 = 0; k0 < H_DIM / 2; k0 += 64) {
        __syncthreads();
#pragma unroll
        for (int j = 0; j < 4; j++) gl_lds16(aP[j], AsB + seg[j]);
#pragma unroll
        for (int j = 0; j < 4; j++) gl_lds16(bP[j], BsB + seg[j]);
#pragma unroll
        for (int j = 0; j < 4; j++) { aP[j] += 64; bP[j] += 64; }
        __syncthreads();

#pragma unroll
        for (int kk = 0; kk < 2; kk++) {
            const int co = ((((kk << 2) | quad)) ^ x7) << 4;
            short8 av[4], bv[4];
#pragma unroll
            for (int i = 0; i < 4; i++) av[i] = *(const short8*)(AsB + rowA[i] + co);
#pragma unroll
            for (int i = 0; i < 4; i++) bv[i] = *(const short8*)(BsB + rowB[i] + co);
#pragma unroll
            for (int mi = 0; mi < 4; mi++)
#pragma unroll
                for (int ni = 0; ni < 4; ni++)
                    acc[mi][ni] = __builtin_amdgcn_mfma_f32_16x16x32_bf16(av[mi], bv[ni], acc[mi][ni], 0, 0, 0);
        }
    }

    float bb[4];
#pragma unroll
    for (int ni = 0; ni < 4; ni++)
        bb[ni] = (kc == 0) ? bias2[e * D_DIM + n0 + wn + ni * 16 + l16] : 0.f;

    float* plane = o_part + (size_t)kc * PLANE;
#pragma unroll
    for (int mi = 0; mi < 4; mi++) {
#pragma unroll
        for (int reg = 0; reg < 4; reg++) {
            int gm = m0 + wm + mi * 16 + quad * 4 + reg;
            if (gm < cnt) {
                float wgt = pair_w[off + gm];
                float* orow = plane + (size_t)(off + gm) * D_DIM + n0 + wn;
#pragma unroll
                for (int ni = 0; ni < 4; ni++)
                    orow[ni * 16 + l16] = (acc[mi][ni][reg] + bb[ni]) * wgt;
            }
        }
    }
}

// -------- combine: out[t] = sum over {2 planes} x {2 pair rows} --------------
__global__ __launch_bounds__(256) void combine_kernel(
    const float* __restrict__ o_part, const int* __restrict__ ppos,
    float* __restrict__ out)
{
    int t = blockIdx.x;
    int d = threadIdx.x * 4;
    size_t p0 = (size_t)ppos[t * 2] * D_DIM + d;
    size_t p1 = (size_t)ppos[t * 2 + 1] * D_DIM + d;
    float4 a = *(const float4*)(o_part + p0);
    float4 b = *(const float4*)(o_part + p1);
    float4 c = *(const float4*)(o_part + PLANE + p0);
    float4 e = *(const float4*)(o_part + PLANE + p1);
    float4 r;
    r.x = a.x + b.x + c.x + e.x;
    r.y = a.y + b.y + c.y + e.y;
    r.z = a.z + b.z + c.z + e.z;
    r.w = a.w + b.w + c.w + e.w;
    *(float4*)(out + (size_t)t * D_DIM + d) = r;
}

extern "C" void kernel_launch(void* const* d_in, const int* in_sizes, int n_in,
                              void* d_out, int out_size, void* d_ws, size_t ws_size,
                              hipStream_t stream)
{
    const float* x  = (const float*)d_in[0];
    const float* rw = (const float*)d_in[1];
    const float* w1 = (const float*)d_in[2];
    const float* b1 = (const float*)d_in[3];
    const float* w2 = (const float*)d_in[4];
    const float* b2 = (const float*)d_in[5];
    float* out = (float*)d_out;

    char* ws = (char*)d_ws;
    int*   counts     = (int*)(ws + 0);
    int*   cursors    = (int*)(ws + 256);
    int*   offsets    = (int*)(ws + 512);
    int*   tile_e     = (int*)(ws + 1024);
    int*   tile_m0    = (int*)(ws + 1536);
    int*   topi       = (int*)(ws + 2048);
    float* topw       = (float*)(ws + 34816);
    int*   pair_token = (int*)(ws + 67584);
    float* pair_w     = (float*)(ws + 100352);
    int*   ppos       = (int*)(ws + 133120);
    ushort* xbf  = (ushort*)(ws + 165888);                        // 8 MiB
    ushort* w1bf = (ushort*)(ws + 8554496ULL);                    // 64 MiB
    ushort* w2bf = (ushort*)(ws + 75663360ULL);                   // 64 MiB
    ushort* h    = (ushort*)(ws + 142772224ULL);                  // 64 MiB
    float* o_part = (float*)(ws + 8554496ULL);                    // 2x32 MiB, overlays w1bf (dead after ffn1)

    hipMemsetAsync(counts, 0, 32, stream);

    const size_t NTOT = (size_t)T_TOK * D_DIM + 2ULL * E_NUM * H_DIM * D_DIM;  // 68M elems
    cvt_all_kernel<<<NTOT / 2048, 256, 0, stream>>>(x, xbf, w1, w1bf, w2, w2bf);

    router_kernel<<<T_TOK / 4, 256, 0, stream>>>(x, rw, counts, topi, topw);
    offsets_tiles_kernel<<<1, 64, 0, stream>>>(counts, offsets, cursors, tile_e, tile_m0);
    assign_kernel<<<T_TOK / 256, 256, 0, stream>>>(topi, topw, cursors, pair_token, pair_w, ppos);

    dim3 g1(MAX_TILES, H_DIM / 128, 1);
    ffn1_kernel<<<g1, 256, 0, stream>>>(xbf, w1bf, b1, counts, offsets, tile_e, tile_m0, pair_token, h);

    dim3 g2(MAX_TILES, D_DIM / 128, 2);
    ffn2_kernel<<<g2, 256, 0, stream>>>(h, w2bf, b2, counts, offsets, tile_e, tile_m0, pair_w, o_part);

    combine_kernel<<<T_TOK, 256, 0, stream>>>(o_part, ppos, out);
}

// Round 6
// 744.941 us; speedup vs baseline: 1.1004x; 1.1004x over previous
//
#include <hip/hip_runtime.h>
#include <stdint.h>

typedef __attribute__((ext_vector_type(8))) short short8;
typedef __attribute__((ext_vector_type(4))) float floatx4;

#define T_TOK 4096
#define D_DIM 1024
#define H_DIM 4096
#define E_NUM 8
#define MAX_TILES 72            // padded to GROUP multiple; real tiles <= 71
#define PLANE (8192ULL * 1024ULL)   // floats per split-K partial plane

static __device__ __forceinline__ ushort f2bf(float f) {
    uint32_t u = __float_as_uint(f);
    u += 0x7FFF + ((u >> 16) & 1);   // round-to-nearest-even
    return (ushort)(u >> 16);
}

static __device__ __forceinline__ uint4 pack8(float4 a, float4 b) {
    union { ushort u[8]; uint4 v; } r;
    r.u[0] = f2bf(a.x); r.u[1] = f2bf(a.y); r.u[2] = f2bf(a.z); r.u[3] = f2bf(a.w);
    r.u[4] = f2bf(b.x); r.u[5] = f2bf(b.y); r.u[6] = f2bf(b.z); r.u[7] = f2bf(b.w);
    return r.v;
}

// async global->LDS, 16B per lane; LDS dest = wave-uniform base + lane*16
static __device__ __forceinline__ void gl_lds16(const void* g, void* l) {
    __builtin_amdgcn_global_load_lds(
        (const __attribute__((address_space(1))) uint32_t*)g,
        (__attribute__((address_space(3))) uint32_t*)l, 16, 0, 0);
}

// ---------------- fused f32 -> bf16 bulk convert (x, w1, w2 in one grid) -----
__global__ __launch_bounds__(256) void cvt_all_kernel(
    const float* __restrict__ x,  ushort* __restrict__ xbf,
    const float* __restrict__ w1, ushort* __restrict__ w1bf,
    const float* __restrict__ w2, ushort* __restrict__ w2bf)
{
    const size_t NX = (size_t)T_TOK * D_DIM;            // 4M
    const size_t NW = (size_t)E_NUM * H_DIM * D_DIM;    // 32M
    size_t i = ((size_t)blockIdx.x * 256 + threadIdx.x) * 8;
    const float* src; ushort* dst; size_t j;
    if (i < NX)           { src = x;  dst = xbf;  j = i; }
    else if (i < NX + NW) { src = w1; dst = w1bf; j = i - NX; }
    else                  { src = w2; dst = w2bf; j = i - NX - NW; }
    float4 a = *(const float4*)(src + j);
    float4 b = *(const float4*)(src + j + 4);
    *(uint4*)(dst + j) = pack8(a, b);
}

// ---------------- Router: logits -> softmax -> top2 -> renorm (all f32) ------
__global__ __launch_bounds__(256) void router_kernel(
    const float* __restrict__ x, const float* __restrict__ rw,
    int* __restrict__ counts, int* __restrict__ topi, float* __restrict__ topw)
{
    __shared__ float rwS[E_NUM * D_DIM];             // 32 KB
    int tid = threadIdx.x;
    for (int i = tid; i < E_NUM * D_DIM / 4; i += 256)
        ((float4*)rwS)[i] = ((const float4*)rw)[i];
    __syncthreads();

    int wave = tid >> 6, lane = tid & 63;
    int t = blockIdx.x * 4 + wave;
    const float* xr = x + (size_t)t * D_DIM;

    float acc[E_NUM];
#pragma unroll
    for (int e = 0; e < E_NUM; e++) acc[e] = 0.f;

    float xv[16];
#pragma unroll
    for (int j = 0; j < 4; j++)
        *(float4*)&xv[j * 4] = ((const float4*)xr)[lane * 4 + j];
#pragma unroll
    for (int j = 0; j < 16; j++) {
        int idx = lane * 16 + j;
#pragma unroll
        for (int e = 0; e < E_NUM; e++)
            acc[e] += xv[j] * rwS[e * D_DIM + idx];
    }
#pragma unroll
    for (int e = 0; e < E_NUM; e++)
        for (int off = 32; off > 0; off >>= 1)
            acc[e] += __shfl_xor(acc[e], off, 64);

    if (lane == 0) {
        float mx = acc[0];
        for (int e = 1; e < E_NUM; e++) mx = fmaxf(mx, acc[e]);
        float p[E_NUM];
        for (int e = 0; e < E_NUM; e++) p[e] = expf(acc[e] - mx);
        int i0 = 0;
        for (int e = 1; e < E_NUM; e++) if (p[e] > p[i0]) i0 = e;   // lowest-idx tie-break
        int i1 = (i0 == 0) ? 1 : 0;
        for (int e = 0; e < E_NUM; e++) if (e != i0 && p[e] > p[i1]) i1 = e;
        float w0 = p[i0], w1 = p[i1], sw = w0 + w1;
        w0 /= sw; w1 /= sw;
        topi[t * 2] = i0; topi[t * 2 + 1] = i1;
        topw[t * 2] = w0; topw[t * 2 + 1] = w1;
        atomicAdd(&counts[i0], 1);
        atomicAdd(&counts[i1], 1);
    }
}

// offsets + exact tile list (kills dead blocks in the GEMM grids)
__global__ void offsets_tiles_kernel(const int* __restrict__ counts,
                                     int* __restrict__ offsets, int* __restrict__ cursors,
                                     int* __restrict__ tile_e, int* __restrict__ tile_m0)
{
    if (threadIdx.x == 0 && blockIdx.x == 0) {
        int off = 0, n = 0;
        for (int e = 0; e < E_NUM; e++) {
            offsets[e] = off; cursors[e] = off; off += counts[e];
            for (int m0 = 0; m0 < counts[e]; m0 += 128) {
                tile_e[n] = e; tile_m0[n] = m0; n++;
            }
        }
        for (; n < MAX_TILES; n++) tile_e[n] = -1;
    }
}

__global__ __launch_bounds__(256) void assign_kernel(
    const int* __restrict__ topi, const float* __restrict__ topw,
    int* __restrict__ cursors, int* __restrict__ pair_token, float* __restrict__ pair_w,
    int* __restrict__ ppos)
{
    int t = blockIdx.x * 256 + threadIdx.x;
    if (t >= T_TOK) return;
    for (int k = 0; k < 2; k++) {
        int e = topi[t * 2 + k];
        int pos = atomicAdd(&cursors[e], 1);
        pair_token[pos] = t;
        pair_w[pos] = topw[t * 2 + k];
        ppos[t * 2 + k] = pos;
    }
}

// ---------------- FFN layer 1: h = gelu(xbf @ w1bf^T + b1) -------------------
// 128x128 tile, BK=64, XOR-swizzled LDS, global_load_lds(16B).
// 1-D grid with grouped supertile swizzle: consecutive ids sweep 8 m-tiles
// then advance n -> co-resident window's working set fits L3 (A/B reuse).
__global__ __launch_bounds__(256) void ffn1_kernel(
    const ushort* __restrict__ xbf, const ushort* __restrict__ w1bf,
    const float* __restrict__ bias1,
    const int* __restrict__ counts, const int* __restrict__ offsets,
    const int* __restrict__ tile_e, const int* __restrict__ tile_m0,
    const int* __restrict__ pair_token, ushort* __restrict__ h)
{
    const int id = blockIdx.x;
    const int g = id >> 8;                 // group of 8 m-tiles x 32 n-tiles
    const int rem = id & 255;
    const int mt = g * 8 + (rem & 7);
    const int nt = rem >> 3;
    int e = tile_e[mt];
    if (e < 0) return;
    int m0 = tile_m0[mt];
    int cnt = counts[e];
    int off = offsets[e];
    int n0 = nt * 128;

    __shared__ ushort As[128 * 64];   // 16 KB
    __shared__ ushort Bs[128 * 64];   // 16 KB

    const int t = threadIdx.x;
    const int wave = t >> 6, lane = t & 63;
    const int wm = (wave >> 1) * 64, wn = (wave & 1) * 64;
    const int quad = lane >> 4, l16 = lane & 15;

    const int rsub = lane >> 3;
    const int cpos = lane & 7;
    const int srcElem = (cpos ^ rsub) * 8;   // XOR swizzle

    const ushort* aP[4];
    const ushort* bP[4];
#pragma unroll
    for (int j = 0; j < 4; j++) {
        int row = j * 32 + wave * 8 + rsub;
        int gr = m0 + row; if (gr >= cnt) gr = cnt - 1;
        aP[j] = xbf + (size_t)pair_token[off + gr] * D_DIM + srcElem;
        bP[j] = w1bf + ((size_t)e * H_DIM + n0 + row) * D_DIM + srcElem;
    }
    char* AsB = (char*)As;
    char* BsB = (char*)Bs;
    int seg[4];
#pragma unroll
    for (int j = 0; j < 4; j++) seg[j] = j * 4096 + wave * 1024;

    int rowA[4], rowB[4];
#pragma unroll
    for (int i = 0; i < 4; i++) {
        rowA[i] = (wm + i * 16 + l16) * 128;
        rowB[i] = (wn + i * 16 + l16) * 128;
    }
    const int x7 = l16 & 7;

    floatx4 acc[4][4] = {};

    for (int k0 = 0; k0 < D_DIM; k0 += 64) {
        __syncthreads();
#pragma unroll
        for (int j = 0; j < 4; j++) gl_lds16(aP[j], AsB + seg[j]);
#pragma unroll
        for (int j = 0; j < 4; j++) gl_lds16(bP[j], BsB + seg[j]);
#pragma unroll
        for (int j = 0; j < 4; j++) { aP[j] += 64; bP[j] += 64; }
        __syncthreads();

#pragma unroll
        for (int kk = 0; kk < 2; kk++) {
            const int co = ((((kk << 2) | quad)) ^ x7) << 4;
            short8 av[4], bv[4];
#pragma unroll
            for (int i = 0; i < 4; i++) av[i] = *(const short8*)(AsB + rowA[i] + co);
#pragma unroll
            for (int i = 0; i < 4; i++) bv[i] = *(const short8*)(BsB + rowB[i] + co);
#pragma unroll
            for (int mi = 0; mi < 4; mi++)
#pragma unroll
                for (int ni = 0; ni < 4; ni++)
                    acc[mi][ni] = __builtin_amdgcn_mfma_f32_16x16x32_bf16(av[mi], bv[ni], acc[mi][ni], 0, 0, 0);
        }
    }

    float bb[4];
#pragma unroll
    for (int ni = 0; ni < 4; ni++) bb[ni] = bias1[e * H_DIM + n0 + wn + ni * 16 + l16];

#pragma unroll
    for (int mi = 0; mi < 4; mi++) {
#pragma unroll
        for (int reg = 0; reg < 4; reg++) {
            int gm = m0 + wm + mi * 16 + quad * 4 + reg;
            if (gm < cnt) {
                ushort* hrow = h + (size_t)(off + gm) * H_DIM + n0 + wn;
#pragma unroll
                for (int ni = 0; ni < 4; ni++) {
                    float v = acc[mi][ni][reg] + bb[ni];
                    v = 0.5f * v * (1.f + erff(v * 0.70710678118654752f));
                    hrow[ni * 16 + l16] = f2bf(v);
                }
            }
        }
    }
}

// ------- FFN layer 2 (split-K x2): o_part[kc] = cw * (h[:,kc] @ w2[:,kc]^T [+ b2]) -------
__global__ __launch_bounds__(256) void ffn2_kernel(
    const ushort* __restrict__ h, const ushort* __restrict__ w2bf,
    const float* __restrict__ bias2,
    const int* __restrict__ counts, const int* __restrict__ offsets,
    const int* __restrict__ tile_e, const int* __restrict__ tile_m0,
    const float* __restrict__ pair_w, float* __restrict__ o_part)
{
    const int id = blockIdx.x;
    const int g = id >> 7;                 // group of 8 m-tiles x (8 n x 2 kc)
    const int rem = id & 127;
    const int mt = g * 8 + (rem & 7);
    const int ntk = rem >> 3;
    const int nt = ntk & 7;
    const int kc = ntk >> 3;
    int e = tile_e[mt];
    if (e < 0) return;
    int m0 = tile_m0[mt];
    int cnt = counts[e];
    int off = offsets[e];
    int n0 = nt * 128;
    const size_t kbase = (size_t)kc * (H_DIM / 2);

    __shared__ ushort As[128 * 64];
    __shared__ ushort Bs[128 * 64];

    const int t = threadIdx.x;
    const int wave = t >> 6, lane = t & 63;
    const int wm = (wave >> 1) * 64, wn = (wave & 1) * 64;
    const int quad = lane >> 4, l16 = lane & 15;

    const int rsub = lane >> 3;
    const int cpos = lane & 7;
    const int srcElem = (cpos ^ rsub) * 8;

    const ushort* aP[4];
    const ushort* bP[4];
#pragma unroll
    for (int j = 0; j < 4; j++) {
        int row = j * 32 + wave * 8 + rsub;
        int gr = m0 + row; if (gr >= cnt) gr = cnt - 1;
        aP[j] = h + (size_t)(off + gr) * H_DIM + kbase + srcElem;
        bP[j] = w2bf + ((size_t)e * D_DIM + n0 + row) * H_DIM + kbase + srcElem;
    }
    char* AsB = (char*)As;
    char* BsB = (char*)Bs;
    int seg[4];
#pragma unroll
    for (int j = 0; j < 4; j++) seg[j] = j * 4096 + wave * 1024;

    int rowA[4], rowB[4];
#pragma unroll
    for (int i = 0; i < 4; i++) {
        rowA[i] = (wm + i * 16 + l16) * 128;
        rowB[i] = (wn + i * 16 + l16) * 128;
    }
    const int x7 = l16 & 7;

    floatx4 acc[4][4] = {};

    for (int k0 = 0; k0 < H_DIM / 2; k0 += 64) {
        __syncthreads();
#pragma unroll
        for (int j = 0; j < 4; j++) gl_lds16(aP[j], AsB + seg[j]);
#pragma unroll
        for (int j = 0; j < 4; j++) gl_lds16(bP[j], BsB + seg[j]);
#pragma unroll
        for (int j = 0; j < 4; j++) { aP[j] += 64; bP[j] += 64; }
        __syncthreads();

#pragma unroll
        for (int kk = 0; kk < 2; kk++) {
            const int co = ((((kk << 2) | quad)) ^ x7) << 4;
            short8 av[4], bv[4];
#pragma unroll
            for (int i = 0; i < 4; i++) av[i] = *(const short8*)(AsB + rowA[i] + co);
#pragma unroll
            for (int i = 0; i < 4; i++) bv[i] = *(const short8*)(BsB + rowB[i] + co);
#pragma unroll
            for (int mi = 0; mi < 4; mi++)
#pragma unroll
                for (int ni = 0; ni < 4; ni++)
                    acc[mi][ni] = __builtin_amdgcn_mfma_f32_16x16x32_bf16(av[mi], bv[ni], acc[mi][ni], 0, 0, 0);
        }
    }

    float bb[4];
#pragma unroll
    for (int ni = 0; ni < 4; ni++)
        bb[ni] = (kc == 0) ? bias2[e * D_DIM + n0 + wn + ni * 16 + l16] : 0.f;

    float* plane = o_part + (size_t)kc * PLANE;
#pragma unroll
    for (int mi = 0; mi < 4; mi++) {
#pragma unroll
        for (int reg = 0; reg < 4; reg++) {
            int gm = m0 + wm + mi * 16 + quad * 4 + reg;
            if (gm < cnt) {
                float wgt = pair_w[off + gm];
                float* orow = plane + (size_t)(off + gm) * D_DIM + n0 + wn;
#pragma unroll
                for (int ni = 0; ni < 4; ni++)
                    orow[ni * 16 + l16] = (acc[mi][ni][reg] + bb[ni]) * wgt;
            }
        }
    }
}

// -------- combine: out[t] = sum over {2 planes} x {2 pair rows} --------------
__global__ __launch_bounds__(256) void combine_kernel(
    const float* __restrict__ o_part, const int* __restrict__ ppos,
    float* __restrict__ out)
{
    int t = blockIdx.x;
    int d = threadIdx.x * 4;
    size_t p0 = (size_t)ppos[t * 2] * D_DIM + d;
    size_t p1 = (size_t)ppos[t * 2 + 1] * D_DIM + d;
    float4 a = *(const float4*)(o_part + p0);
    float4 b = *(const float4*)(o_part + p1);
    float4 c = *(const float4*)(o_part + PLANE + p0);
    float4 e = *(const float4*)(o_part + PLANE + p1);
    float4 r;
    r.x = a.x + b.x + c.x + e.x;
    r.y = a.y + b.y + c.y + e.y;
    r.z = a.z + b.z + c.z + e.z;
    r.w = a.w + b.w + c.w + e.w;
    *(float4*)(out + (size_t)t * D_DIM + d) = r;
}

extern "C" void kernel_launch(void* const* d_in, const int* in_sizes, int n_in,
                              void* d_out, int out_size, void* d_ws, size_t ws_size,
                              hipStream_t stream)
{
    const float* x  = (const float*)d_in[0];
    const float* rw = (const float*)d_in[1];
    const float* w1 = (const float*)d_in[2];
    const float* b1 = (const float*)d_in[3];
    const float* w2 = (const float*)d_in[4];
    const float* b2 = (const float*)d_in[5];
    float* out = (float*)d_out;

    char* ws = (char*)d_ws;
    int*   counts     = (int*)(ws + 0);
    int*   cursors    = (int*)(ws + 256);
    int*   offsets    = (int*)(ws + 512);
    int*   tile_e     = (int*)(ws + 1024);
    int*   tile_m0    = (int*)(ws + 1536);
    int*   topi       = (int*)(ws + 2048);
    float* topw       = (float*)(ws + 34816);
    int*   pair_token = (int*)(ws + 67584);
    float* pair_w     = (float*)(ws + 100352);
    int*   ppos       = (int*)(ws + 133120);
    ushort* xbf  = (ushort*)(ws + 165888);                        // 8 MiB
    ushort* w1bf = (ushort*)(ws + 8554496ULL);                    // 64 MiB
    ushort* w2bf = (ushort*)(ws + 75663360ULL);                   // 64 MiB
    ushort* h    = (ushort*)(ws + 142772224ULL);                  // 64 MiB
    float* o_part = (float*)(ws + 8554496ULL);                    // 2x32 MiB, overlays w1bf (dead after ffn1)

    hipMemsetAsync(counts, 0, 32, stream);

    const size_t NTOT = (size_t)T_TOK * D_DIM + 2ULL * E_NUM * H_DIM * D_DIM;  // 68M elems
    cvt_all_kernel<<<NTOT / 2048, 256, 0, stream>>>(x, xbf, w1, w1bf, w2, w2bf);

    router_kernel<<<T_TOK / 4, 256, 0, stream>>>(x, rw, counts, topi, topw);
    offsets_tiles_kernel<<<1, 64, 0, stream>>>(counts, offsets, cursors, tile_e, tile_m0);
    assign_kernel<<<T_TOK / 256, 256, 0, stream>>>(topi, topw, cursors, pair_token, pair_w, ppos);

    ffn1_kernel<<<MAX_TILES * 32, 256, 0, stream>>>(xbf, w1bf, b1, counts, offsets, tile_e, tile_m0, pair_token, h);

    ffn2_kernel<<<MAX_TILES * 16, 256, 0, stream>>>(h, w2bf, b2, counts, offsets, tile_e, tile_m0, pair_w, o_part);

    combine_kernel<<<T_TOK, 256, 0, stream>>>(o_part, ppos, out);
}